// Round 8
// baseline (200.762 us; speedup 1.0000x reference)
//
#include <hip/hip_runtime.h>
#include <cmath>

#define NUM_HEADS 8
#define MAX_POINTS 8
#define HD 64

typedef short bf16x8 __attribute__((ext_vector_type(8)));
typedef float f32x4 __attribute__((ext_vector_type(4)));
typedef float f32x2 __attribute__((ext_vector_type(2)));

typedef const __attribute__((address_space(1))) unsigned int gu32;
typedef __attribute__((address_space(3))) unsigned int lu32;

__device__ __forceinline__ unsigned short f2bf(float f) {
    unsigned u = __float_as_uint(f);
    unsigned r = (u + 0x7fff + ((u >> 16) & 1)) >> 16;   // RNE
    return (unsigned short)r;
}
__device__ __forceinline__ unsigned packbf2(float a, float b) {
    return (unsigned)f2bf(a) | ((unsigned)f2bf(b) << 16);
}
// one u32 (2 packed bf16) -> f32x2 {lo, hi}
__device__ __forceinline__ f32x2 bfpair(unsigned u) {
    f32x2 r;
    r.x = __uint_as_float(u << 16);
    r.y = __uint_as_float(u & 0xffff0000u);
    return r;
}
__device__ __forceinline__ f32x2 sp2(float v) { return (f32x2){v, v}; }
// forced packed fp32 math (2 FMA/inst).  Non-volatile: scheduler may reorder.
// Numerically identical to scalar fma per half.
__device__ __forceinline__ f32x2 pkfma(f32x2 a, f32x2 b, f32x2 c) {
    f32x2 d;
    asm("v_pk_fma_f32 %0, %1, %2, %3" : "=v"(d) : "v"(a), "v"(b), "v"(c));
    return d;
}
__device__ __forceinline__ f32x2 pkmul(f32x2 a, f32x2 b) {
    f32x2 d;
    asm("v_pk_mul_f32 %0, %1, %2" : "=v"(d) : "v"(a), "v"(b));
    return d;
}

// ---------------------------------------------------------------------------
// Merged prep kernel: one launch for
//   [0, 8192)        : query fp32 -> bf16 convert   (1024 elems/block)
//   [8192, 16384)    : ref (B: 512x4096) transpose+convert -> refT (4096x512)
//   [16384, 17152)   : weight transposes q_w / off_w / out_w
// ---------------------------------------------------------------------------
__global__ __launch_bounds__(256) void prep_k(
    const float* __restrict__ query, unsigned short* __restrict__ qin_bf,
    const float* __restrict__ ref, unsigned short* __restrict__ refT,
    const float* __restrict__ q_w, const float* __restrict__ off_w,
    const float* __restrict__ out_w, unsigned short* __restrict__ wcat,
    unsigned short* __restrict__ woutT)
{
    __shared__ float tile[32][33];
    int bid = blockIdx.x;
    int tid = threadIdx.x;

    if (bid < 8192) {
        // ---- cvt: query fp32 -> bf16 ----
        int i = (bid * 256 + tid) * 4;
        float4 v = *(const float4*)&query[i];
        ushort4 o;
        o.x = f2bf(v.x); o.y = f2bf(v.y); o.z = f2bf(v.z); o.w = f2bf(v.w);
        *(ushort4*)&qin_bf[i] = o;
        return;
    }
    int tx = tid & 31, ty = tid >> 5;
    if (bid < 16384) {
        // ---- ref transpose: per batch in (K=512, N=4096) -> out (N, K) ----
        int b2 = bid - 8192;
        int z = b2 >> 11;             // batch (2048 blocks each)
        int r = b2 & 2047;
        int k0 = (r & 15) * 32;       // over K=512
        int n0 = (r >> 4) * 32;       // over N=4096
        size_t ib = (size_t)z * 512 * 4096;
#pragma unroll
        for (int i = 0; i < 32; i += 8)
            tile[ty + i][tx] = ref[ib + (size_t)(k0 + ty + i) * 4096 + n0 + tx];
        __syncthreads();
#pragma unroll
        for (int i = 0; i < 32; i += 8)
            refT[ib + (size_t)(n0 + ty + i) * 512 + k0 + tx] = f2bf(tile[tx][ty + i]);
        return;
    }
    // ---- weight transposes ----
    int b3 = bid - 16384;             // [0, 768)
    int z = b3 >> 8;
    int r = b3 & 255;
    int k0 = (r & 15) * 32;
    int n0 = (r >> 4) * 32;
    const float* in; unsigned short* out; int N;
    if (z == 0)      { in = q_w;   out = wcat;             N = 512; }
    else if (z == 1) { in = off_w; out = wcat + 512 * 512; N = 128;
                       if (n0 >= 128) return; }
    else             { in = out_w; out = woutT;            N = 512; }
#pragma unroll
    for (int i = 0; i < 32; i += 8)
        tile[ty + i][tx] = in[(size_t)(k0 + ty + i) * N + n0 + tx];
    __syncthreads();
#pragma unroll
    for (int i = 0; i < 32; i += 8)
        out[(size_t)(n0 + ty + i) * 512 + k0 + tx] = f2bf(tile[tx][ty + i]);
}

// ---------------------------------------------------------------------------
// Shared MFMA inner loop: 128x128 tile, BK=32, double-buffered LDS,
// 2-phase pipeline: issue next tile's global_load_lds BEFORE computing
// current tile; ONE barrier per K-step.
// ---------------------------------------------------------------------------
__device__ __forceinline__ void gemm128_core(
    const unsigned short* A, const unsigned short* BT, int K,
    int bm, int bn, int tid, unsigned short* As, unsigned short* Bs,
    f32x4 (&acc)[4][4])
{
    int wave = tid >> 6, lane = tid & 63;
    int quad = lane >> 4, l16 = lane & 15;
    int wm = (wave >> 1) * 64, wn = (wave & 1) * 64;
    int srow = tid >> 2, sq = (tid & 3) * 8;
    const unsigned short* aP0 = &A[(size_t)(bm + srow) * K + sq];
    const unsigned short* aP1 = aP0 + (size_t)64 * K;
    const unsigned short* bP0 = &BT[(size_t)(bn + srow) * K + sq];
    const unsigned short* bP1 = bP0 + (size_t)64 * K;

#define STAGE(buf, k0)                                                         \
    do {                                                                       \
        lu32* aL0 = (lu32*)&As[(buf) * 4096 + wave * 512];                     \
        lu32* aL1 = (lu32*)&As[(buf) * 4096 + 2048 + wave * 512];              \
        lu32* bL0 = (lu32*)&Bs[(buf) * 4096 + wave * 512];                     \
        lu32* bL1 = (lu32*)&Bs[(buf) * 4096 + 2048 + wave * 512];              \
        __builtin_amdgcn_global_load_lds((gu32*)(aP0 + (k0)), aL0, 16, 0, 0);  \
        __builtin_amdgcn_global_load_lds((gu32*)(aP1 + (k0)), aL1, 16, 0, 0);  \
        __builtin_amdgcn_global_load_lds((gu32*)(bP0 + (k0)), bL0, 16, 0, 0);  \
        __builtin_amdgcn_global_load_lds((gu32*)(bP1 + (k0)), bL1, 16, 0, 0);  \
    } while (0)

    STAGE(0, 0);
    __syncthreads();                 // drains vmcnt(0): buf0 ready
    int cur = 0;
    for (int k0 = 0; k0 < K; k0 += 32) {
        if (k0 + 32 < K) STAGE(cur ^ 1, k0 + 32);   // prefetch next tile
        bf16x8 af[4], bfr[4];
#pragma unroll
        for (int t = 0; t < 4; ++t) {
            af[t]  = *(const bf16x8*)&As[cur * 4096 + (wm + t * 16 + l16) * 32 + quad * 8];
            bfr[t] = *(const bf16x8*)&Bs[cur * 4096 + (wn + t * 16 + l16) * 32 + quad * 8];
        }
#pragma unroll
        for (int mt = 0; mt < 4; ++mt)
#pragma unroll
            for (int nt = 0; nt < 4; ++nt)
                acc[mt][nt] = __builtin_amdgcn_mfma_f32_16x16x32_bf16(
                    af[mt], bfr[nt], acc[mt][nt], 0, 0, 0);
        __syncthreads();             // orders buffer swap + drains prefetch
        cur ^= 1;
    }
#undef STAGE
}

// ---------------------------------------------------------------------------
// Fused q+offset projection GEMM: A (M,512) @ BTcat (640,512)^T.
// ---------------------------------------------------------------------------
__global__ __launch_bounds__(256) void gemm_qoff_k(
    const unsigned short* __restrict__ A, const unsigned short* __restrict__ BT,
    const float* __restrict__ q_b, const float* __restrict__ off_b,
    unsigned short* __restrict__ qout, float* __restrict__ offout,
    int M, int K)
{
    __shared__ unsigned short As[2 * 128 * 32];
    __shared__ unsigned short Bs[2 * 128 * 32];
    int tid = threadIdx.x;
    int wave = tid >> 6, lane = tid & 63;
    int quad = lane >> 4, l16 = lane & 15;
    int bm = blockIdx.y * 128, bn = blockIdx.x * 128;
    int wm = (wave >> 1) * 64, wn = (wave & 1) * 64;

    f32x4 acc[4][4];
#pragma unroll
    for (int i = 0; i < 4; ++i)
#pragma unroll
        for (int j = 0; j < 4; ++j) acc[i][j] = (f32x4){0.f, 0.f, 0.f, 0.f};

    gemm128_core(A, BT, K, bm, bn, tid, As, Bs, acc);

#pragma unroll
    for (int mt = 0; mt < 4; ++mt)
#pragma unroll
        for (int nt = 0; nt < 4; ++nt) {
            int r0 = bm + wm + mt * 16 + quad * 4;
            int c  = bn + wn + nt * 16 + l16;
            if (bn < 512) {
                float bv = q_b[c];
#pragma unroll
                for (int r = 0; r < 4; ++r)
                    qout[(size_t)(r0 + r) * 512 + c] = f2bf(acc[mt][nt][r] + bv);
            } else {
                int co = c - 512;
                float bv = off_b[co];
#pragma unroll
                for (int r = 0; r < 4; ++r)
                    offout[(size_t)(r0 + r) * 128 + co] = acc[mt][nt][r] + bv;
            }
        }
}

// ---------------------------------------------------------------------------
// Output projection GEMM: fp32 out + bias.
// ---------------------------------------------------------------------------
__global__ __launch_bounds__(256) void gemm_out_k(
    const unsigned short* __restrict__ A, const unsigned short* __restrict__ BT,
    const float* __restrict__ bias, float* __restrict__ Cf, int M, int N, int K)
{
    __shared__ unsigned short As[2 * 128 * 32];
    __shared__ unsigned short Bs[2 * 128 * 32];
    int tid = threadIdx.x;
    int wave = tid >> 6, lane = tid & 63;
    int quad = lane >> 4, l16 = lane & 15;
    int bm = blockIdx.y * 128, bn = blockIdx.x * 128;
    int wm = (wave >> 1) * 64, wn = (wave & 1) * 64;

    f32x4 acc[4][4];
#pragma unroll
    for (int i = 0; i < 4; ++i)
#pragma unroll
        for (int j = 0; j < 4; ++j) acc[i][j] = (f32x4){0.f, 0.f, 0.f, 0.f};

    gemm128_core(A, BT, K, bm, bn, tid, As, Bs, acc);

#pragma unroll
    for (int mt = 0; mt < 4; ++mt)
#pragma unroll
        for (int nt = 0; nt < 4; ++nt) {
            int r0 = bm + wm + mt * 16 + quad * 4;
            int c  = bn + wn + nt * 16 + l16;
            float bv = bias[c];
#pragma unroll
            for (int r = 0; r < 4; ++r)
                Cf[(size_t)(r0 + r) * N + c] = acc[mt][nt][r] + bv;
        }
}

// ---------------------------------------------------------------------------
// Fused bilinear sample + softmax attention — ONLINE (no-max) version with
// forced v_pk_fma_f32 packed math.  Structure identical to the verified r7
// kernel (no per-thread arrays, nothing live across a barrier, one barrier);
// only the blend/dot/accumulate fma chains are replaced by pk asm
// (bit-identical numerics, half the VALU instruction count).
// ---------------------------------------------------------------------------
__global__ __launch_bounds__(256) void sample_attn_sp_k(
    const unsigned short* __restrict__ qb, const float* __restrict__ offb,
    const unsigned short* __restrict__ refT, unsigned short* __restrict__ ob,
    const int* __restrict__ npp)
{
    __shared__ f32x2 spart[2][4][64];                  // [q][pair][lane]
    __shared__ float ssum[2][64];                      // [q][lane]
    int npts = *npp;
    int tid = threadIdx.x;
    int qsel = tid >> 7;              // query within block
    int w = (tid >> 6) & 1;           // wave within query (points 4w..4w+3)
    int lane = tid & 63;
    int h = lane >> 3;
    int j = lane & 7;
    int coff = (h << 6) + (j << 3);

    // XCD swizzle: b = (blockIdx&7)>>1
    int bi = blockIdx.x;
    int grp = bi & 7;
    int b = grp >> 1;
    int idx = ((bi >> 3) << 1) | (grp & 1);   // [0,2048)
    int n = (idx << 1) | qsel;                // [0,4096)
    int bn = (b << 12) | n;
    int row = n >> 6, col = n & 63;

    uint4 qu = *(const uint4*)&qb[(bn << 9) + coff];
    f32x2 qv0 = bfpair(qu.x), qv1 = bfpair(qu.y);
    f32x2 qv2 = bfpair(qu.z), qv3 = bfpair(qu.w);

    // this wave's 4 points' offsets
    const float* op = offb + (bn << 7) + (h << 4) + (w << 3);
    const unsigned short* rb = refT + ((size_t)b << 21) + coff;

    f32x2 oa0 = {0.f, 0.f}, oa1 = {0.f, 0.f}, oa2 = {0.f, 0.f}, oa3 = {0.f, 0.f};
    float s = 0.f;

#pragma unroll
    for (int p = 0; p < 4; ++p) {
        float2 od = *(const float2*)(op + p * 2);
        float x = (float)row + od.x;   // matches reference's coord quirk
        float y = (float)col + od.y;
        float x0f = floorf(x), y0f = floorf(y);
        int x0 = (int)x0f, y0 = (int)y0f;
        float wx1 = x - x0f, wx0 = 1.f - wx1;
        float wy1 = y - y0f, wy0 = 1.f - wy1;
        float wya = ((unsigned)y0       < 64u) ? wy0 : 0.f;
        float wyb = ((unsigned)(y0 + 1) < 64u) ? wy1 : 0.f;
        float wxa = ((unsigned)x0       < 64u) ? wx0 : 0.f;
        float wxb = ((unsigned)(x0 + 1) < 64u) ? wx1 : 0.f;
        int yc0 = min(max(y0, 0), 63), yc1 = min(max(y0 + 1, 0), 63);
        int xc0 = min(max(x0, 0), 63), xc1 = min(max(x0 + 1, 0), 63);
        const unsigned short* ry0 = rb + (yc0 << 15);
        const unsigned short* ry1 = rb + (yc1 << 15);
        uint4 u00 = *(const uint4*)(ry0 + (xc0 << 9));
        uint4 u01 = *(const uint4*)(ry0 + (xc1 << 9));
        uint4 u10 = *(const uint4*)(ry1 + (xc0 << 9));
        uint4 u11 = *(const uint4*)(ry1 + (xc1 << 9));

        f32x2 w00 = sp2(wya * wxa), w01 = sp2(wya * wxb);
        f32x2 w10 = sp2(wyb * wxa), w11 = sp2(wyb * wxb);

        f32x2 a0 = pkmul(w00, bfpair(u00.x));
        f32x2 a1 = pkmul(w00, bfpair(u00.y));
        f32x2 a2 = pkmul(w00, bfpair(u00.z));
        f32x2 a3 = pkmul(w00, bfpair(u00.w));
        a0 = pkfma(w01, bfpair(u01.x), a0);
        a1 = pkfma(w01, bfpair(u01.y), a1);
        a2 = pkfma(w01, bfpair(u01.z), a2);
        a3 = pkfma(w01, bfpair(u01.w), a3);
        a0 = pkfma(w10, bfpair(u10.x), a0);
        a1 = pkfma(w10, bfpair(u10.y), a1);
        a2 = pkfma(w10, bfpair(u10.z), a2);
        a3 = pkfma(w10, bfpair(u10.w), a3);
        a0 = pkfma(w11, bfpair(u11.x), a0);
        a1 = pkfma(w11, bfpair(u11.y), a1);
        a2 = pkfma(w11, bfpair(u11.z), a2);
        a3 = pkfma(w11, bfpair(u11.w), a3);

        // logit: q . sv, reduced over the 8-lane head group
        f32x2 t2 = pkmul(qv0, a0);
        t2 = pkfma(qv1, a1, t2);
        t2 = pkfma(qv2, a2, t2);
        t2 = pkfma(qv3, a3, t2);
        float t = t2.x + t2.y;
        t += __shfl_xor(t, 1);
        t += __shfl_xor(t, 2);
        t += __shfl_xor(t, 4);

        // online accumulate (no max subtraction; logits are O(1))
        float e = ((w * 4 + p) < npts) ? __expf(t * 0.125f) : 0.f;
        f32x2 ev = sp2(e);
        oa0 = pkfma(ev, a0, oa0);
        oa1 = pkfma(ev, a1, oa1);
        oa2 = pkfma(ev, a2, oa2);
        oa3 = pkfma(ev, a3, oa3);
        s += e;
    }

    if (w == 1) {
        spart[qsel][0][lane] = oa0;
        spart[qsel][1][lane] = oa1;
        spart[qsel][2][lane] = oa2;
        spart[qsel][3][lane] = oa3;
        ssum[qsel][lane] = s;
    }
    __syncthreads();
    if (w == 0) {
        oa0 = oa0 + spart[qsel][0][lane];
        oa1 = oa1 + spart[qsel][1][lane];
        oa2 = oa2 + spart[qsel][2][lane];
        oa3 = oa3 + spart[qsel][3][lane];
        float inv = 1.f / (s + ssum[qsel][lane]);
        f32x2 iv = sp2(inv);
        oa0 = pkmul(oa0, iv); oa1 = pkmul(oa1, iv);
        oa2 = pkmul(oa2, iv); oa3 = pkmul(oa3, iv);
        uint4 o;
        o.x = packbf2(oa0.x, oa0.y);
        o.y = packbf2(oa1.x, oa1.y);
        o.z = packbf2(oa2.x, oa2.y);
        o.w = packbf2(oa3.x, oa3.y);
        *(uint4*)&ob[(bn << 9) + coff] = o;
    }
}

// ---------------------------------------------------------------------------
// Launch
// ---------------------------------------------------------------------------
extern "C" void kernel_launch(void* const* d_in, const int* in_sizes, int n_in,
                              void* d_out, int out_size, void* d_ws, size_t ws_size,
                              hipStream_t stream) {
    const float* query = (const float*)d_in[0];
    const float* ref   = (const float*)d_in[1];
    const float* q_w   = (const float*)d_in[2];
    const float* q_b   = (const float*)d_in[3];
    // d_in[4], d_in[5]: kv_w, kv_b -- unused by the reference forward
    const float* off_w = (const float*)d_in[6];
    const float* off_b = (const float*)d_in[7];
    const float* out_w = (const float*)d_in[8];
    const float* out_b = (const float*)d_in[9];
    const int* npp  = (const int*)d_in[12];

    const int C = 512;
    const int B = 4;
    const int N = 64 * 64;            // 4096
    const int M = B * N;              // 16384
    const int OFFD = NUM_HEADS * MAX_POINTS * 2;  // 128

    float* offbuf = (float*)d_ws;                                   // M*OFFD f32
    unsigned short* refT_bf = (unsigned short*)(offbuf + (size_t)M * OFFD); // M*C
    unsigned short* qin_bf  = refT_bf + (size_t)M * C;              // M*C
    unsigned short* qbuf_bf = qin_bf  + (size_t)M * C;              // M*C
    unsigned short* obuf_bf = qbuf_bf + (size_t)M * C;              // M*C
    unsigned short* wcat    = obuf_bf + (size_t)M * C;              // (C+OFFD)*C
    unsigned short* woutT   = wcat + (size_t)(C + OFFD) * C;        // C*C

    dim3 blk(256);
    // merged prep: query cvt + ref transpose + weight transposes
    prep_k<<<dim3(8192 + 8192 + 768), blk, 0, stream>>>(
        query, qin_bf, ref, refT_bf, q_w, off_w, out_w, wcat, woutT);

    // fused q + offset projection (N = 640)
    gemm_qoff_k<<<dim3(5, M / 128), blk, 0, stream>>>(
        qin_bf, wcat, q_b, off_b, qbuf_bf, offbuf, M, C);

    // fused sample + attention -> bf16 obuf (2 queries/block, 2 waves/query)
    sample_attn_sp_k<<<dim3(M / 2), blk, 0, stream>>>(
        qbuf_bf, offbuf, refT_bf, obuf_bf, npp);

    // output projection (fp32 out)
    gemm_out_k<<<dim3(C / 128, M / 128), blk, 0, stream>>>(
        obuf_bf, woutT, out_b, (float*)d_out, M, C, C);
}

// Round 9
// 200.376 us; speedup vs baseline: 1.0019x; 1.0019x over previous
//
#include <hip/hip_runtime.h>
#include <cmath>

#define NUM_HEADS 8
#define MAX_POINTS 8
#define HD 64

typedef short bf16x8 __attribute__((ext_vector_type(8)));
typedef float f32x4 __attribute__((ext_vector_type(4)));
typedef float f32x2 __attribute__((ext_vector_type(2)));

typedef const __attribute__((address_space(1))) unsigned int gu32;
typedef __attribute__((address_space(3))) unsigned int lu32;

__device__ __forceinline__ unsigned short f2bf(float f) {
    unsigned u = __float_as_uint(f);
    unsigned r = (u + 0x7fff + ((u >> 16) & 1)) >> 16;   // RNE
    return (unsigned short)r;
}
__device__ __forceinline__ unsigned packbf2(float a, float b) {
    return (unsigned)f2bf(a) | ((unsigned)f2bf(b) << 16);
}
// one u32 (2 packed bf16) -> f32x2 {lo, hi}
__device__ __forceinline__ f32x2 bfpair(unsigned u) {
    f32x2 r;
    r.x = __uint_as_float(u << 16);
    r.y = __uint_as_float(u & 0xffff0000u);
    return r;
}
__device__ __forceinline__ f32x2 sp2(float v) { return (f32x2){v, v}; }

// ---------------------------------------------------------------------------
// Merged prep kernel: one launch for
//   [0, 8192)        : query fp32 -> bf16 convert   (1024 elems/block)
//   [8192, 16384)    : ref (B: 512x4096) transpose+convert -> refT (4096x512)
//   [16384, 17152)   : weight transposes q_w / off_w / out_w
// ---------------------------------------------------------------------------
__global__ __launch_bounds__(256) void prep_k(
    const float* __restrict__ query, unsigned short* __restrict__ qin_bf,
    const float* __restrict__ ref, unsigned short* __restrict__ refT,
    const float* __restrict__ q_w, const float* __restrict__ off_w,
    const float* __restrict__ out_w, unsigned short* __restrict__ wcat,
    unsigned short* __restrict__ woutT)
{
    __shared__ float tile[32][33];
    int bid = blockIdx.x;
    int tid = threadIdx.x;

    if (bid < 8192) {
        // ---- cvt: query fp32 -> bf16 ----
        int i = (bid * 256 + tid) * 4;
        float4 v = *(const float4*)&query[i];
        ushort4 o;
        o.x = f2bf(v.x); o.y = f2bf(v.y); o.z = f2bf(v.z); o.w = f2bf(v.w);
        *(ushort4*)&qin_bf[i] = o;
        return;
    }
    int tx = tid & 31, ty = tid >> 5;
    if (bid < 16384) {
        // ---- ref transpose: per batch in (K=512, N=4096) -> out (N, K) ----
        int b2 = bid - 8192;
        int z = b2 >> 11;             // batch (2048 blocks each)
        int r = b2 & 2047;
        int k0 = (r & 15) * 32;       // over K=512
        int n0 = (r >> 4) * 32;       // over N=4096
        size_t ib = (size_t)z * 512 * 4096;
#pragma unroll
        for (int i = 0; i < 32; i += 8)
            tile[ty + i][tx] = ref[ib + (size_t)(k0 + ty + i) * 4096 + n0 + tx];
        __syncthreads();
#pragma unroll
        for (int i = 0; i < 32; i += 8)
            refT[ib + (size_t)(n0 + ty + i) * 512 + k0 + tx] = f2bf(tile[tx][ty + i]);
        return;
    }
    // ---- weight transposes ----
    int b3 = bid - 16384;             // [0, 768)
    int z = b3 >> 8;
    int r = b3 & 255;
    int k0 = (r & 15) * 32;
    int n0 = (r >> 4) * 32;
    const float* in; unsigned short* out; int N;
    if (z == 0)      { in = q_w;   out = wcat;             N = 512; }
    else if (z == 1) { in = off_w; out = wcat + 512 * 512; N = 128;
                       if (n0 >= 128) return; }
    else             { in = out_w; out = woutT;            N = 512; }
#pragma unroll
    for (int i = 0; i < 32; i += 8)
        tile[ty + i][tx] = in[(size_t)(k0 + ty + i) * N + n0 + tx];
    __syncthreads();
#pragma unroll
    for (int i = 0; i < 32; i += 8)
        out[(size_t)(n0 + ty + i) * 512 + k0 + tx] = f2bf(tile[tx][ty + i]);
}

// ---------------------------------------------------------------------------
// Shared MFMA inner loop: 128x128 tile, BK=32, double-buffered LDS,
// 2-phase pipeline: issue next tile's global_load_lds BEFORE computing
// current tile; ONE barrier per K-step.
// ---------------------------------------------------------------------------
__device__ __forceinline__ void gemm128_core(
    const unsigned short* A, const unsigned short* BT, int K,
    int bm, int bn, int tid, unsigned short* As, unsigned short* Bs,
    f32x4 (&acc)[4][4])
{
    int wave = tid >> 6, lane = tid & 63;
    int quad = lane >> 4, l16 = lane & 15;
    int wm = (wave >> 1) * 64, wn = (wave & 1) * 64;
    int srow = tid >> 2, sq = (tid & 3) * 8;
    const unsigned short* aP0 = &A[(size_t)(bm + srow) * K + sq];
    const unsigned short* aP1 = aP0 + (size_t)64 * K;
    const unsigned short* bP0 = &BT[(size_t)(bn + srow) * K + sq];
    const unsigned short* bP1 = bP0 + (size_t)64 * K;

#define STAGE(buf, k0)                                                         \
    do {                                                                       \
        lu32* aL0 = (lu32*)&As[(buf) * 4096 + wave * 512];                     \
        lu32* aL1 = (lu32*)&As[(buf) * 4096 + 2048 + wave * 512];              \
        lu32* bL0 = (lu32*)&Bs[(buf) * 4096 + wave * 512];                     \
        lu32* bL1 = (lu32*)&Bs[(buf) * 4096 + 2048 + wave * 512];              \
        __builtin_amdgcn_global_load_lds((gu32*)(aP0 + (k0)), aL0, 16, 0, 0);  \
        __builtin_amdgcn_global_load_lds((gu32*)(aP1 + (k0)), aL1, 16, 0, 0);  \
        __builtin_amdgcn_global_load_lds((gu32*)(bP0 + (k0)), bL0, 16, 0, 0);  \
        __builtin_amdgcn_global_load_lds((gu32*)(bP1 + (k0)), bL1, 16, 0, 0);  \
    } while (0)

    STAGE(0, 0);
    __syncthreads();                 // drains vmcnt(0): buf0 ready
    int cur = 0;
    for (int k0 = 0; k0 < K; k0 += 32) {
        if (k0 + 32 < K) STAGE(cur ^ 1, k0 + 32);   // prefetch next tile
        bf16x8 af[4], bfr[4];
#pragma unroll
        for (int t = 0; t < 4; ++t) {
            af[t]  = *(const bf16x8*)&As[cur * 4096 + (wm + t * 16 + l16) * 32 + quad * 8];
            bfr[t] = *(const bf16x8*)&Bs[cur * 4096 + (wn + t * 16 + l16) * 32 + quad * 8];
        }
#pragma unroll
        for (int mt = 0; mt < 4; ++mt)
#pragma unroll
            for (int nt = 0; nt < 4; ++nt)
                acc[mt][nt] = __builtin_amdgcn_mfma_f32_16x16x32_bf16(
                    af[mt], bfr[nt], acc[mt][nt], 0, 0, 0);
        __syncthreads();             // orders buffer swap + drains prefetch
        cur ^= 1;
    }
#undef STAGE
}

// ---------------------------------------------------------------------------
// Fused q+offset projection GEMM: A (M,512) @ BTcat (640,512)^T.
// ---------------------------------------------------------------------------
__global__ __launch_bounds__(256) void gemm_qoff_k(
    const unsigned short* __restrict__ A, const unsigned short* __restrict__ BT,
    const float* __restrict__ q_b, const float* __restrict__ off_b,
    unsigned short* __restrict__ qout, float* __restrict__ offout,
    int M, int K)
{
    __shared__ unsigned short As[2 * 128 * 32];
    __shared__ unsigned short Bs[2 * 128 * 32];
    int tid = threadIdx.x;
    int wave = tid >> 6, lane = tid & 63;
    int quad = lane >> 4, l16 = lane & 15;
    int bm = blockIdx.y * 128, bn = blockIdx.x * 128;
    int wm = (wave >> 1) * 64, wn = (wave & 1) * 64;

    f32x4 acc[4][4];
#pragma unroll
    for (int i = 0; i < 4; ++i)
#pragma unroll
        for (int j = 0; j < 4; ++j) acc[i][j] = (f32x4){0.f, 0.f, 0.f, 0.f};

    gemm128_core(A, BT, K, bm, bn, tid, As, Bs, acc);

#pragma unroll
    for (int mt = 0; mt < 4; ++mt)
#pragma unroll
        for (int nt = 0; nt < 4; ++nt) {
            int r0 = bm + wm + mt * 16 + quad * 4;
            int c  = bn + wn + nt * 16 + l16;
            if (bn < 512) {
                float bv = q_b[c];
#pragma unroll
                for (int r = 0; r < 4; ++r)
                    qout[(size_t)(r0 + r) * 512 + c] = f2bf(acc[mt][nt][r] + bv);
            } else {
                int co = c - 512;
                float bv = off_b[co];
#pragma unroll
                for (int r = 0; r < 4; ++r)
                    offout[(size_t)(r0 + r) * 128 + co] = acc[mt][nt][r] + bv;
            }
        }
}

// ---------------------------------------------------------------------------
// Output projection GEMM: fp32 out + bias.
// ---------------------------------------------------------------------------
__global__ __launch_bounds__(256) void gemm_out_k(
    const unsigned short* __restrict__ A, const unsigned short* __restrict__ BT,
    const float* __restrict__ bias, float* __restrict__ Cf, int M, int N, int K)
{
    __shared__ unsigned short As[2 * 128 * 32];
    __shared__ unsigned short Bs[2 * 128 * 32];
    int tid = threadIdx.x;
    int wave = tid >> 6, lane = tid & 63;
    int quad = lane >> 4, l16 = lane & 15;
    int bm = blockIdx.y * 128, bn = blockIdx.x * 128;
    int wm = (wave >> 1) * 64, wn = (wave & 1) * 64;

    f32x4 acc[4][4];
#pragma unroll
    for (int i = 0; i < 4; ++i)
#pragma unroll
        for (int j = 0; j < 4; ++j) acc[i][j] = (f32x4){0.f, 0.f, 0.f, 0.f};

    gemm128_core(A, BT, K, bm, bn, tid, As, Bs, acc);

#pragma unroll
    for (int mt = 0; mt < 4; ++mt)
#pragma unroll
        for (int nt = 0; nt < 4; ++nt) {
            int r0 = bm + wm + mt * 16 + quad * 4;
            int c  = bn + wn + nt * 16 + l16;
            float bv = bias[c];
#pragma unroll
            for (int r = 0; r < 4; ++r)
                Cf[(size_t)(r0 + r) * N + c] = acc[mt][nt][r] + bv;
        }
}

// ---------------------------------------------------------------------------
// Fused bilinear sample + softmax attention — ONLINE (no-max), 2 points/wave.
// Block = 256 threads = 4 waves = ONE query; wave w handles points 2w, 2w+1.
// Halves the serial gather chain vs 4 points/wave and doubles independent
// waves (pk-fma null in r8 -> latency-bound, not VALU-bound).  Structure
// keeps the r7 invariants: no per-thread arrays, nothing live across the
// barrier, one barrier; 3 waves publish partials, wave 0 merges.
// ---------------------------------------------------------------------------
__global__ __launch_bounds__(256) void sample_attn_sp_k(
    const unsigned short* __restrict__ qb, const float* __restrict__ offb,
    const unsigned short* __restrict__ refT, unsigned short* __restrict__ ob,
    const int* __restrict__ npp)
{
    __shared__ f32x2 spart[3][4][64];                  // [wave-1][pair][lane]
    __shared__ float ssum[3][64];                      // [wave-1][lane]
    int npts = *npp;
    int tid = threadIdx.x;
    int w = tid >> 6;                 // wave 0..3: points 2w, 2w+1
    int lane = tid & 63;
    int h = lane >> 3;
    int j = lane & 7;
    int coff = (h << 6) + (j << 3);

    // XCD swizzle: batch b lands on XCDs {2b, 2b+1}
    int bi = blockIdx.x;
    int grp = bi & 7;
    int b = grp >> 1;
    int n = ((bi >> 3) << 1) | (grp & 1);     // [0,4096)
    int bn = (b << 12) | n;
    int row = n >> 6, col = n & 63;

    uint4 qu = *(const uint4*)&qb[(bn << 9) + coff];
    f32x2 qv0 = bfpair(qu.x), qv1 = bfpair(qu.y);
    f32x2 qv2 = bfpair(qu.z), qv3 = bfpair(qu.w);

    // this wave's 2 points' offsets
    const float* op = offb + (bn << 7) + (h << 4) + (w << 2);
    const unsigned short* rb = refT + ((size_t)b << 21) + coff;

    f32x2 oa0 = {0.f, 0.f}, oa1 = {0.f, 0.f}, oa2 = {0.f, 0.f}, oa3 = {0.f, 0.f};
    float s = 0.f;

#pragma unroll
    for (int p = 0; p < 2; ++p) {
        float2 od = *(const float2*)(op + p * 2);
        float x = (float)row + od.x;   // matches reference's coord quirk
        float y = (float)col + od.y;
        float x0f = floorf(x), y0f = floorf(y);
        int x0 = (int)x0f, y0 = (int)y0f;
        float wx1 = x - x0f, wx0 = 1.f - wx1;
        float wy1 = y - y0f, wy0 = 1.f - wy1;
        float wya = ((unsigned)y0       < 64u) ? wy0 : 0.f;
        float wyb = ((unsigned)(y0 + 1) < 64u) ? wy1 : 0.f;
        float wxa = ((unsigned)x0       < 64u) ? wx0 : 0.f;
        float wxb = ((unsigned)(x0 + 1) < 64u) ? wx1 : 0.f;
        int yc0 = min(max(y0, 0), 63), yc1 = min(max(y0 + 1, 0), 63);
        int xc0 = min(max(x0, 0), 63), xc1 = min(max(x0 + 1, 0), 63);
        const unsigned short* ry0 = rb + (yc0 << 15);
        const unsigned short* ry1 = rb + (yc1 << 15);
        uint4 u00 = *(const uint4*)(ry0 + (xc0 << 9));
        uint4 u01 = *(const uint4*)(ry0 + (xc1 << 9));
        uint4 u10 = *(const uint4*)(ry1 + (xc0 << 9));
        uint4 u11 = *(const uint4*)(ry1 + (xc1 << 9));

        f32x2 w00 = sp2(wya * wxa), w01 = sp2(wya * wxb);
        f32x2 w10 = sp2(wyb * wxa), w11 = sp2(wyb * wxb);

        f32x2 a0 = w00 * bfpair(u00.x);
        f32x2 a1 = w00 * bfpair(u00.y);
        f32x2 a2 = w00 * bfpair(u00.z);
        f32x2 a3 = w00 * bfpair(u00.w);
        a0 = __builtin_elementwise_fma(w01, bfpair(u01.x), a0);
        a1 = __builtin_elementwise_fma(w01, bfpair(u01.y), a1);
        a2 = __builtin_elementwise_fma(w01, bfpair(u01.z), a2);
        a3 = __builtin_elementwise_fma(w01, bfpair(u01.w), a3);
        a0 = __builtin_elementwise_fma(w10, bfpair(u10.x), a0);
        a1 = __builtin_elementwise_fma(w10, bfpair(u10.y), a1);
        a2 = __builtin_elementwise_fma(w10, bfpair(u10.z), a2);
        a3 = __builtin_elementwise_fma(w10, bfpair(u10.w), a3);
        a0 = __builtin_elementwise_fma(w11, bfpair(u11.x), a0);
        a1 = __builtin_elementwise_fma(w11, bfpair(u11.y), a1);
        a2 = __builtin_elementwise_fma(w11, bfpair(u11.z), a2);
        a3 = __builtin_elementwise_fma(w11, bfpair(u11.w), a3);

        // logit: q . sv, reduced over the 8-lane head group
        f32x2 t2 = qv0 * a0;
        t2 = __builtin_elementwise_fma(qv1, a1, t2);
        t2 = __builtin_elementwise_fma(qv2, a2, t2);
        t2 = __builtin_elementwise_fma(qv3, a3, t2);
        float t = t2.x + t2.y;
        t += __shfl_xor(t, 1);
        t += __shfl_xor(t, 2);
        t += __shfl_xor(t, 4);

        // online accumulate (no max subtraction; logits are O(1))
        float e = ((w * 2 + p) < npts) ? __expf(t * 0.125f) : 0.f;
        f32x2 ev = sp2(e);
        oa0 = __builtin_elementwise_fma(ev, a0, oa0);
        oa1 = __builtin_elementwise_fma(ev, a1, oa1);
        oa2 = __builtin_elementwise_fma(ev, a2, oa2);
        oa3 = __builtin_elementwise_fma(ev, a3, oa3);
        s += e;
    }

    if (w) {
        spart[w - 1][0][lane] = oa0;
        spart[w - 1][1][lane] = oa1;
        spart[w - 1][2][lane] = oa2;
        spart[w - 1][3][lane] = oa3;
        ssum[w - 1][lane] = s;
    }
    __syncthreads();
    if (w == 0) {
#pragma unroll
        for (int k = 0; k < 3; ++k) {
            oa0 = oa0 + spart[k][0][lane];
            oa1 = oa1 + spart[k][1][lane];
            oa2 = oa2 + spart[k][2][lane];
            oa3 = oa3 + spart[k][3][lane];
            s += ssum[k][lane];
        }
        float inv = 1.f / s;
        f32x2 iv = sp2(inv);
        oa0 = oa0 * iv; oa1 = oa1 * iv; oa2 = oa2 * iv; oa3 = oa3 * iv;
        uint4 o;
        o.x = packbf2(oa0.x, oa0.y);
        o.y = packbf2(oa1.x, oa1.y);
        o.z = packbf2(oa2.x, oa2.y);
        o.w = packbf2(oa3.x, oa3.y);
        *(uint4*)&ob[(bn << 9) + coff] = o;
    }
}

// ---------------------------------------------------------------------------
// Launch
// ---------------------------------------------------------------------------
extern "C" void kernel_launch(void* const* d_in, const int* in_sizes, int n_in,
                              void* d_out, int out_size, void* d_ws, size_t ws_size,
                              hipStream_t stream) {
    const float* query = (const float*)d_in[0];
    const float* ref   = (const float*)d_in[1];
    const float* q_w   = (const float*)d_in[2];
    const float* q_b   = (const float*)d_in[3];
    // d_in[4], d_in[5]: kv_w, kv_b -- unused by the reference forward
    const float* off_w = (const float*)d_in[6];
    const float* off_b = (const float*)d_in[7];
    const float* out_w = (const float*)d_in[8];
    const float* out_b = (const float*)d_in[9];
    const int* npp  = (const int*)d_in[12];

    const int C = 512;
    const int B = 4;
    const int N = 64 * 64;            // 4096
    const int M = B * N;              // 16384
    const int OFFD = NUM_HEADS * MAX_POINTS * 2;  // 128

    float* offbuf = (float*)d_ws;                                   // M*OFFD f32
    unsigned short* refT_bf = (unsigned short*)(offbuf + (size_t)M * OFFD); // M*C
    unsigned short* qin_bf  = refT_bf + (size_t)M * C;              // M*C
    unsigned short* qbuf_bf = qin_bf  + (size_t)M * C;              // M*C
    unsigned short* obuf_bf = qbuf_bf + (size_t)M * C;              // M*C
    unsigned short* wcat    = obuf_bf + (size_t)M * C;              // (C+OFFD)*C
    unsigned short* woutT   = wcat + (size_t)(C + OFFD) * C;        // C*C

    dim3 blk(256);
    // merged prep: query cvt + ref transpose + weight transposes
    prep_k<<<dim3(8192 + 8192 + 768), blk, 0, stream>>>(
        query, qin_bf, ref, refT_bf, q_w, off_w, out_w, wcat, woutT);

    // fused q + offset projection (N = 640)
    gemm_qoff_k<<<dim3(5, M / 128), blk, 0, stream>>>(
        qin_bf, wcat, q_b, off_b, qbuf_bf, offbuf, M, C);

    // fused sample + attention -> bf16 obuf (1 query/block, 2 points/wave)
    sample_attn_sp_k<<<dim3(M), blk, 0, stream>>>(
        qbuf_bf, offbuf, refT_bf, obuf_bf, npp);

    // output projection (fp32 out)
    gemm_out_k<<<dim3(C / 128, M / 128), blk, 0, stream>>>(
        obuf_bf, woutT, out_b, (float*)d_out, M, C, C);
}